// Round 4
// baseline (349.752 us; speedup 1.0000x reference)
//
#include <hip/hip_runtime.h>

#define B_ROWS 14336
#define D_DIM  512
#define C_CLS  7
#define M_CLS  2048

typedef __attribute__((ext_vector_type(8))) short bf16x8;
typedef __attribute__((ext_vector_type(4))) float f32x4;

__device__ __forceinline__ short bf16_rne(float x) {
  unsigned u = __float_as_uint(x);
  u += 0x7fffu + ((u >> 16) & 1u);
  return (short)(u >> 16);
}

// K0: fea->bf16 + row norms + logits + zero all accumulators.
// 448 blocks * 4 waves, 8 rows/wave. No atomics (stats moved to k_gram).
__global__ __launch_bounds__(256) void k_prep(const float* __restrict__ fea,
                                              const float* __restrict__ W,
                                              short* __restrict__ fb,
                                              float* __restrict__ an,
                                              float* __restrict__ logits,
                                              float* __restrict__ zb,     // 64 floats: S1,S2,S
                                              float* __restrict__ rowsum) {
  int t = threadIdx.x;
  int gid = blockIdx.x * 256 + t;
  if (gid < 14336) rowsum[gid] = 0.f;
  if (gid < 64) zb[gid] = 0.f;

  int wave = t >> 6, lane = t & 63;
  int gw = blockIdx.x * 4 + wave;
  for (int it = 0; it < 8; ++it) {
    int row = gw + it * 1792;
    const float4* fr4 = (const float4*)(fea + (size_t)row * D_DIM);
    float4 v0 = fr4[lane * 2], v1 = fr4[lane * 2 + 1];
    float s = v0.x * v0.x + v0.y * v0.y + v0.z * v0.z + v0.w * v0.w +
              v1.x * v1.x + v1.y * v1.y + v1.z * v1.z + v1.w * v1.w;
#pragma unroll
    for (int o = 1; o < 64; o <<= 1) s += __shfl_xor(s, o);
    if (lane == 0) an[row] = s;
    // pack 8 bf16 -> int4, one 16B store per lane
    int4 pk;
    pk.x = (unsigned short)bf16_rne(v0.x) | ((unsigned)(unsigned short)bf16_rne(v0.y) << 16);
    pk.y = (unsigned short)bf16_rne(v0.z) | ((unsigned)(unsigned short)bf16_rne(v0.w) << 16);
    pk.z = (unsigned short)bf16_rne(v1.x) | ((unsigned)(unsigned short)bf16_rne(v1.y) << 16);
    pk.w = (unsigned short)bf16_rne(v1.z) | ((unsigned)(unsigned short)bf16_rne(v1.w) << 16);
    ((int4*)(fb + (size_t)row * D_DIM))[lane] = pk;
#pragma unroll
    for (int c = 0; c < 7; ++c) {
      const float4* w4 = (const float4*)(W + c * D_DIM);
      float4 w0 = w4[lane * 2], w1 = w4[lane * 2 + 1];
      float p = v0.x * w0.x + v0.y * w0.y + v0.z * w0.z + v0.w * w0.w +
                v1.x * w1.x + v1.y * w1.y + v1.z * w1.z + v1.w * w1.w;
#pragma unroll
      for (int o = 1; o < 64; o <<= 1) p += __shfl_xor(p, o);
      if (lane == 0) logits[row * 7 + c] = p;
    }
  }
}

// K1: fused Gram + distance + exp reductions, REGISTER-DIRECT (no LDS, no barriers).
// Each wave owns a 64x64 output tile; block = 2x2 waves = 128x128.
// A/B fragments loaded straight from global in MFMA A-layout:
//   lane(q,s) reads 16B at row (base + s), k-offset q*8 shorts. Double-buffered
//   in registers; compiler emits fine-grained vmcnt — waves never co-stall.
// Grid: 952 self upper-tri + 1536 cross (TJ-major) + 56 stats blocks = 2544.
__global__ __launch_bounds__(256, 3) void k_gram(const short* __restrict__ fb,
                                                 const float* __restrict__ an,
                                                 const float* __restrict__ logits,
                                                 float* __restrict__ S,
                                                 float* __restrict__ rowsum,
                                                 float* __restrict__ S1,
                                                 float* __restrict__ S2) {
  int bid = blockIdx.x;
  int t = threadIdx.x, lane = t & 63, wave = t >> 6;

  if (bid >= 2488) {  // batch-norm stats partials (S1/S2 zeroed by k_prep)
    int sb = bid - 2488;         // 7 classes x 8 chunks
    int c = sb >> 3, chunk = sb & 7;
    int r0 = chunk * 1792;
    float s1 = 0.f, s2 = 0.f;
    for (int j = t; j < 1792; j += 256) {
      float v = logits[(r0 + j) * 7 + c];
      s1 += v;
      s2 += v * v;
    }
#pragma unroll
    for (int o = 1; o < 64; o <<= 1) {
      s1 += __shfl_xor(s1, o);
      s2 += __shfl_xor(s2, o);
    }
    __shared__ float r1_[4], r2_[4];
    if (lane == 0) { r1_[wave] = s1; r2_[wave] = s2; }
    __syncthreads();
    if (t == 0) {
      atomicAdd(&S1[c], r1_[0] + r1_[1] + r1_[2] + r1_[3]);
      atomicAdd(&S2[c], r2_[0] + r2_[1] + r2_[2] + r2_[3]);
    }
    return;
  }

  int c1, c2, TI, TJ, Sidx;
  bool self;
  if (bid < 952) {
    int b = bid / 136;
    int tr = bid - b * 136;
    int tj = 0, t2 = tr;
    while (t2 > tj) { t2 -= (tj + 1); ++tj; }  // (ti<=tj) upper-tri enum
    TI = t2; TJ = tj;
    c1 = b; c2 = b; Sidx = b; self = true;
  } else {
    int e = bid - 952;            // TJ-major: 96 consecutive blocks share B(cls0,TJ)
    TJ = e / 96;
    int r = e - TJ * 96;
    int i = r >> 4; TI = r & 15;
    c1 = i + 1; c2 = 0; Sidx = 7 + i; self = false;
  }
  bool diag = self && (TI == TJ);
  bool off  = self && (TI < TJ);
  int rowA0 = c1 * M_CLS + TI * 128;
  int rowB0 = c2 * M_CLS + TJ * 128;

  int wr = wave >> 1, wc = wave & 1;
  int q = lane >> 4, s = lane & 15;

  // per-lane fragment base offsets (elements)
  int offA[4], offB[4];
#pragma unroll
  for (int mi = 0; mi < 4; ++mi)
    offA[mi] = (rowA0 + wr * 64 + mi * 16 + s) * D_DIM + q * 8;
#pragma unroll
  for (int mj = 0; mj < 4; ++mj)
    offB[mj] = (rowB0 + wc * 64 + mj * 16 + s) * D_DIM + q * 8;

  f32x4 acc[4][4];
#pragma unroll
  for (int i = 0; i < 4; ++i)
#pragma unroll
    for (int j = 0; j < 4; ++j)
      acc[i][j] = (f32x4){0.f, 0.f, 0.f, 0.f};

  bf16x8 a0[4], b0[4], a1[4], b1[4];
#pragma unroll
  for (int m = 0; m < 4; ++m) {
    a0[m] = *(const bf16x8*)(fb + offA[m]);
    b0[m] = *(const bf16x8*)(fb + offB[m]);
  }
  for (int kt = 0; kt < 16; kt += 2) {
    int o1 = (kt + 1) * 32;
#pragma unroll
    for (int m = 0; m < 4; ++m) {
      a1[m] = *(const bf16x8*)(fb + offA[m] + o1);
      b1[m] = *(const bf16x8*)(fb + offB[m] + o1);
    }
#pragma unroll
    for (int mi = 0; mi < 4; ++mi)
#pragma unroll
      for (int mj = 0; mj < 4; ++mj)
        acc[mi][mj] = __builtin_amdgcn_mfma_f32_16x16x32_bf16(
            a0[mi], b0[mj], acc[mi][mj], 0, 0, 0);
    int o2 = (kt + 2 < 16) ? (kt + 2) * 32 : 15 * 32;  // clamped dead prefetch
#pragma unroll
    for (int m = 0; m < 4; ++m) {
      a0[m] = *(const bf16x8*)(fb + offA[m] + o2);
      b0[m] = *(const bf16x8*)(fb + offB[m] + o2);
    }
#pragma unroll
    for (int mi = 0; mi < 4; ++mi)
#pragma unroll
      for (int mj = 0; mj < 4; ++mj)
        acc[mi][mj] = __builtin_amdgcn_mfma_f32_16x16x32_bf16(
            a1[mi], b1[mj], acc[mi][mj], 0, 0, 0);
  }

  // row norms (L2-hot scalar loads)
  float anA[4][4], anB[4];
#pragma unroll
  for (int mi = 0; mi < 4; ++mi)
#pragma unroll
    for (int rg = 0; rg < 4; ++rg)
      anA[mi][rg] = an[rowA0 + wr * 64 + mi * 16 + q * 4 + rg];
#pragma unroll
  for (int mj = 0; mj < 4; ++mj)
    anB[mj] = an[rowB0 + wc * 64 + mj * 16 + s];

  // Epilogue. C/D layout (16x16x32): col = lane&15, row = (lane>>4)*4 + reg.
  // 5-kernel sum via exp-squaring from e1 = exp(-0.05*d2).
  float blockAcc = 0.f;
  float colAcc[4] = {0.f, 0.f, 0.f, 0.f};
#pragma unroll
  for (int mi = 0; mi < 4; ++mi) {
#pragma unroll
    for (int rg = 0; rg < 4; ++rg) {
      int rl = wr * 64 + mi * 16 + q * 4 + rg;
      float aA = anA[mi][rg];
      float rowAcc = 0.f;
#pragma unroll
      for (int mj = 0; mj < 4; ++mj) {
        int cl = wc * 64 + mj * 16 + s;
        float g = acc[mi][mj][rg];
        float d2 = fmaxf(aA + anB[mj] - 2.f * g, 0.f);
        if (diag && rl == cl) d2 = 0.f;  // exact diagonal
        float e1 = __expf(-0.05f * d2);
        float e2 = e1 * e1, e4 = e2 * e2, e8 = e4 * e4, e16 = e8 * e8;
        blockAcc += e1 + e2 + e4 + e8 + e16;
        if (self) {
          float ek = __expf(-12.5f * d2);  // KDE: 1/(2*0.2^2)
          rowAcc += ek;
          if (off) colAcc[mj] += ek;
        }
      }
      if (self) {
        rowAcc += __shfl_xor(rowAcc, 1);
        rowAcc += __shfl_xor(rowAcc, 2);
        rowAcc += __shfl_xor(rowAcc, 4);
        rowAcc += __shfl_xor(rowAcc, 8);
        if (s == 0) atomicAdd(&rowsum[rowA0 + rl], rowAcc);
      }
    }
  }
  if (off) {
#pragma unroll
    for (int mj = 0; mj < 4; ++mj) {
      float v = colAcc[mj];
      v += __shfl_xor(v, 16);
      v += __shfl_xor(v, 32);
      if (q == 0) atomicAdd(&rowsum[rowB0 + wc * 64 + mj * 16 + s], v);
    }
    blockAcc *= 2.f;  // mirror tile
  }
#pragma unroll
  for (int o = 1; o < 64; o <<= 1) blockAcc += __shfl_xor(blockAcc, o);
  if (lane == 0) atomicAdd(&S[Sidx], blockAcc);
}

// K2: bnout (blocks 0..391) + KDE weights + affinity (block 392).
__global__ __launch_bounds__(256) void k_final(const float* __restrict__ logits,
                                               const float* __restrict__ S1,
                                               const float* __restrict__ S2,
                                               const float* __restrict__ gamma,
                                               const float* __restrict__ beta,
                                               const float* __restrict__ S,
                                               const float* __restrict__ rowsum,
                                               float* __restrict__ out) {
  int b = blockIdx.x, t = threadIdx.x;
  if (b < 392) {
    int idx = b * 256 + t;  // 392*256 = 100352 exactly
    int row = idx / 7;
    int c = idx - row * 7;
    float mu = S1[c] * (1.f / 14336.f);
    float var = S2[c] * (1.f / 14336.f) - mu * mu;
    out[idx] = gamma[c] * (logits[idx] - mu) * rsqrtf(var + 1e-5f) + beta[c];
    return;
  }
  // KDE volumes + affinity loss, single block
  int lane = t & 63, wave = t >> 6;
  // log_norm = -256*ln(2*pi*0.04) - ln(2048)
  const float LOG_NORM = 345.9110632f;
  __shared__ float red[4];
  __shared__ float w7[7];
  for (int c = 0; c < 7; ++c) {
    float v = 0.f;
    for (int i = t; i < M_CLS; i += 256)
      v += 1.f / (logf(rowsum[c * M_CLS + i]) + LOG_NORM);
#pragma unroll
    for (int o = 1; o < 64; o <<= 1) v += __shfl_xor(v, o);
    if (lane == 0) red[wave] = v;
    __syncthreads();
    if (t == 0) w7[c] = 1.f / ((red[0] + red[1] + red[2] + red[3]) + 1e-5f);
    __syncthreads();
  }
  if (t == 0) {
    const float inv_m2 = 1.0f / ((float)M_CLS * (float)M_CLS);
    float aff = 0.f;
#pragma unroll
    for (int i = 0; i < 7; ++i) {
      float Ssrc = S[i];
      float Stgt = (i > 0) ? S[0] : S[1];
      float X    = (i > 0) ? S[6 + i] : S[7];  // cross Sidx 7+j is (j+1,0); X01==X10
      aff -= (Ssrc + Stgt - 2.f * X) * inv_m2 * w7[i];
    }
    out[100352] = aff;
  }
}

extern "C" void kernel_launch(void* const* d_in, const int* in_sizes, int n_in,
                              void* d_out, int out_size, void* d_ws, size_t ws_size,
                              hipStream_t stream) {
  const float* fea   = (const float*)d_in[0];
  const float* W_fc  = (const float*)d_in[1];
  const float* gamma = (const float*)d_in[2];
  const float* beta  = (const float*)d_in[3];
  float* out = (float*)d_out;

  char* ws = (char*)d_ws;
  short* fb = (short*)ws;                        // bf16 fea: 14,680,064 B
  float* fbase  = (float*)(ws + 14680064);
  float* an     = fbase;                         // 14336
  float* logits = fbase + 14336;                 // 100352
  float* zb     = fbase + 114688;                // 64-float zero block:
  float* S1     = zb;                            //   [0..6]
  float* S2     = zb + 7;                        //   [7..13]
  float* S      = zb + 16;                       //   [16..28] (13 used)
  float* rowsum = fbase + 114752;                // 14336

  k_prep <<<448,  256, 0, stream>>>(fea, W_fc, fb, an, logits, zb, rowsum);
  k_gram <<<2544, 256, 0, stream>>>(fb, an, logits, S, rowsum, S1, S2);
  k_final<<<393,  256, 0, stream>>>(logits, S1, S2, gamma, beta, S, rowsum, out);
}

// Round 5
// 258.829 us; speedup vs baseline: 1.3513x; 1.3513x over previous
//
#include <hip/hip_runtime.h>

#define B_ROWS 14336
#define D_DIM  512
#define C_CLS  7
#define M_CLS  2048

typedef __attribute__((ext_vector_type(8))) short bf16x8;
typedef __attribute__((ext_vector_type(4))) float f32x4;

typedef const __attribute__((address_space(1))) short gshort_t;
typedef __attribute__((address_space(3))) short lshort_t;

__device__ __forceinline__ void gload16(const short* g, short* l) {
  // async global->LDS DMA, 16B/lane, dest = wave-uniform base + lane*16
  __builtin_amdgcn_global_load_lds((gshort_t*)g, (lshort_t*)l, 16, 0, 0);
}

__device__ __forceinline__ short bf16_rne(float x) {
  unsigned u = __float_as_uint(x);
  u += 0x7fffu + ((u >> 16) & 1u);
  return (short)(u >> 16);
}

// K0: fea->bf16 + row norms + logits + zero small accumulators.
// 448 blocks * 4 waves, 8 rows/wave.
__global__ __launch_bounds__(256) void k_prep(const float* __restrict__ fea,
                                              const float* __restrict__ W,
                                              short* __restrict__ fb,
                                              float* __restrict__ an,
                                              float* __restrict__ logits,
                                              float* __restrict__ zb) {  // 64 floats: S1,S2,S
  int t = threadIdx.x;
  if (blockIdx.x == 0 && t < 64) zb[t] = 0.f;

  int wave = t >> 6, lane = t & 63;
  int gw = blockIdx.x * 4 + wave;
  for (int it = 0; it < 8; ++it) {
    int row = gw + it * 1792;
    const float4* fr4 = (const float4*)(fea + (size_t)row * D_DIM);
    float4 v0 = fr4[lane * 2], v1 = fr4[lane * 2 + 1];
    float s = v0.x * v0.x + v0.y * v0.y + v0.z * v0.z + v0.w * v0.w +
              v1.x * v1.x + v1.y * v1.y + v1.z * v1.z + v1.w * v1.w;
#pragma unroll
    for (int o = 1; o < 64; o <<= 1) s += __shfl_xor(s, o);
    if (lane == 0) an[row] = s;
    int4 pk;
    pk.x = (unsigned short)bf16_rne(v0.x) | ((unsigned)(unsigned short)bf16_rne(v0.y) << 16);
    pk.y = (unsigned short)bf16_rne(v0.z) | ((unsigned)(unsigned short)bf16_rne(v0.w) << 16);
    pk.z = (unsigned short)bf16_rne(v1.x) | ((unsigned)(unsigned short)bf16_rne(v1.y) << 16);
    pk.w = (unsigned short)bf16_rne(v1.z) | ((unsigned)(unsigned short)bf16_rne(v1.w) << 16);
    ((int4*)(fb + (size_t)row * D_DIM))[lane] = pk;
#pragma unroll
    for (int c = 0; c < 7; ++c) {
      const float4* w4 = (const float4*)(W + c * D_DIM);
      float4 w0 = w4[lane * 2], w1 = w4[lane * 2 + 1];
      float p = v0.x * w0.x + v0.y * w0.y + v0.z * w0.z + v0.w * w0.w +
                v1.x * w1.x + v1.y * w1.y + v1.z * w1.z + v1.w * w1.w;
#pragma unroll
      for (int o = 1; o < 64; o <<= 1) p += __shfl_xor(p, o);
      if (lane == 0) logits[row * 7 + c] = p;
    }
  }
}

// K1: fused Gram + distance + exp reductions (r2 structure: 128x128 tile, BK=64,
// DMA staging w/ XOR swizzle, 2 barriers/kt) + XCD-aware block ordering +
// atomic-free rowsum partials.
// Physical grid 2544 = 318 units x 8 XCDs (bid&7 = xcd).
//   xcd<7, unit<136  : self tile (class=xcd, tri-enum unit)   [2MB L2 footprint]
//   else unit<311    : cross tile e = xcd<7 ? xcd*175+unit-136 : 1225+unit
//                      pair p=e>>8 (c1=p+1,c2=0), TJ-major within pair [4MB]
//   unit>=311        : BN-stats partial block (7x8 = 56)
__global__ __launch_bounds__(256) void k_gram(const short* __restrict__ fb,
                                              const float* __restrict__ an,
                                              const float* __restrict__ logits,
                                              float* __restrict__ S,
                                              float* __restrict__ rs_part,
                                              float* __restrict__ S1,
                                              float* __restrict__ S2) {
  int unit = blockIdx.x >> 3, xcd = blockIdx.x & 7;
  int t = threadIdx.x, lane = t & 63, wave = t >> 6;

  if (unit >= 311) {  // batch-norm stats partials (S1/S2 zeroed by k_prep)
    int sidx = (unit - 311) * 8 + xcd;  // 0..55
    int c = sidx >> 3, chunk = sidx & 7;
    int r0 = chunk * 1792;
    float s1 = 0.f, s2 = 0.f;
    for (int j = t; j < 1792; j += 256) {
      float v = logits[(r0 + j) * 7 + c];
      s1 += v;
      s2 += v * v;
    }
#pragma unroll
    for (int o = 1; o < 64; o <<= 1) {
      s1 += __shfl_xor(s1, o);
      s2 += __shfl_xor(s2, o);
    }
    __shared__ float r1_[4], r2_[4];
    if (lane == 0) { r1_[wave] = s1; r2_[wave] = s2; }
    __syncthreads();
    if (t == 0) {
      atomicAdd(&S1[c], r1_[0] + r1_[1] + r1_[2] + r1_[3]);
      atomicAdd(&S2[c], r2_[0] + r2_[1] + r2_[2] + r2_[3]);
    }
    return;
  }

  int c1, c2, TI, TJ, Sidx;
  bool self;
  if (xcd < 7 && unit < 136) {
    int tj = 0, t2 = unit;
    while (t2 > tj) { t2 -= (tj + 1); ++tj; }  // idx = tj*(tj+1)/2 + ti, ti<=tj
    TI = t2; TJ = tj;
    c1 = xcd; c2 = xcd; Sidx = xcd; self = true;
  } else {
    int e = (xcd < 7) ? (xcd * 175 + unit - 136) : (1225 + unit);
    int p = e >> 8;
    int tl = e & 255;
    TJ = tl >> 4; TI = tl & 15;
    c1 = p + 1; c2 = 0; Sidx = 7 + p; self = false;
  }
  bool diag = self && (TI == TJ);
  bool off  = self && (TI < TJ);
  int rowA0 = c1 * M_CLS + TI * 128;
  int rowB0 = c2 * M_CLS + TJ * 128;

  __shared__ short lA[128 * 64];
  __shared__ short lB[128 * 64];

  f32x4 acc[4][4];
#pragma unroll
  for (int i = 0; i < 4; ++i)
#pragma unroll
    for (int j = 0; j < 4; ++j)
      acc[i][j] = (f32x4){0.f, 0.f, 0.f, 0.f};

  int wr = wave >> 1, wc = wave & 1;  // 2x2 waves of 64x64
  int q = lane >> 4, s = lane & 15;

  // physical 16B-seg for frag reads (XOR-swizzled staging)
  int ps0 = q ^ (s & 7);
  int ps1 = (4 + q) ^ (s & 7);

  int srow = wave * 32 + (lane >> 3);
  int sseg = lane & 7;

  for (int kt = 0; kt < 8; ++kt) {
    int k0 = kt * 64;
#pragma unroll
    for (int p2 = 0; p2 < 4; ++p2) {
      int row = srow + p2 * 8;
      int gseg = sseg ^ (row & 7);
      size_t goff = (size_t)row * 512 + k0 + gseg * 8;
      gload16(fb + (size_t)rowA0 * 512 + goff, &lA[(wave * 32 + p2 * 8) * 64]);
      if (!diag)
        gload16(fb + (size_t)rowB0 * 512 + goff, &lB[(wave * 32 + p2 * 8) * 64]);
    }
    __syncthreads();
    const short* lBs = diag ? lA : lB;
#pragma unroll
    for (int kk = 0; kk < 64; kk += 32) {
      int ps = (kk == 0) ? ps0 : ps1;
      bf16x8 af[4], bfv[4];
#pragma unroll
      for (int mi = 0; mi < 4; ++mi)
        af[mi] = *(const bf16x8*)&lA[(wr * 64 + mi * 16 + s) * 64 + ps * 8];
#pragma unroll
      for (int mj = 0; mj < 4; ++mj)
        bfv[mj] = *(const bf16x8*)&lBs[(wc * 64 + mj * 16 + s) * 64 + ps * 8];
#pragma unroll
      for (int mi = 0; mi < 4; ++mi)
#pragma unroll
        for (int mj = 0; mj < 4; ++mj)
          acc[mi][mj] = __builtin_amdgcn_mfma_f32_16x16x32_bf16(
              af[mi], bfv[mj], acc[mi][mj], 0, 0, 0);
    }
    __syncthreads();
  }

  // row norms into registers (L2-hot, lane-redundant loads coalesce/broadcast)
  float anA[4][4], anB[4];
#pragma unroll
  for (int mi = 0; mi < 4; ++mi)
#pragma unroll
    for (int rg = 0; rg < 4; ++rg)
      anA[mi][rg] = an[rowA0 + wr * 64 + mi * 16 + q * 4 + rg];
#pragma unroll
  for (int mj = 0; mj < 4; ++mj)
    anB[mj] = an[rowB0 + wc * 64 + mj * 16 + s];

  // Epilogue. C/D layout (16x16x32): col = lane&15, row = (lane>>4)*4 + reg.
  // 5-kernel sum via exp-squaring from e1 = exp(-0.05*d2).
  // KDE partials: plain stores, unique writer per (slot, row):
  //   direct slot = TJ*2+wc (rows of TI range), mirror slot = TI*2+wr (rows of TJ).
  float blockAcc = 0.f;
  float colAcc[4] = {0.f, 0.f, 0.f, 0.f};
  float* dirP = rs_part + (size_t)(TJ * 2 + wc) * 14336 + rowA0;
#pragma unroll
  for (int mi = 0; mi < 4; ++mi) {
#pragma unroll
    for (int rg = 0; rg < 4; ++rg) {
      int rl = wr * 64 + mi * 16 + q * 4 + rg;
      float aA = anA[mi][rg];
      float rowAcc = 0.f;
#pragma unroll
      for (int mj = 0; mj < 4; ++mj) {
        int cl = wc * 64 + mj * 16 + s;
        float g = acc[mi][mj][rg];
        float d2 = fmaxf(aA + anB[mj] - 2.f * g, 0.f);
        if (diag && rl == cl) d2 = 0.f;  // exact diagonal
        float e1 = __expf(-0.05f * d2);
        float e2 = e1 * e1, e4 = e2 * e2, e8 = e4 * e4, e16 = e8 * e8;
        blockAcc += e1 + e2 + e4 + e8 + e16;
        if (self) {
          float ek = __expf(-12.5f * d2);  // KDE: 1/(2*0.2^2)
          rowAcc += ek;
          if (off) colAcc[mj] += ek;
        }
      }
      if (self) {
        rowAcc += __shfl_xor(rowAcc, 1);
        rowAcc += __shfl_xor(rowAcc, 2);
        rowAcc += __shfl_xor(rowAcc, 4);
        rowAcc += __shfl_xor(rowAcc, 8);
        if (s == 0) dirP[rl] = rowAcc;
      }
    }
  }
  if (off) {
    float* mirP = rs_part + (size_t)(TI * 2 + wr) * 14336 + rowB0;
#pragma unroll
    for (int mj = 0; mj < 4; ++mj) {
      float v = colAcc[mj];
      v += __shfl_xor(v, 16);
      v += __shfl_xor(v, 32);
      if (q == 0) mirP[wc * 64 + mj * 16 + s] = v;
    }
    blockAcc *= 2.f;  // mirror tile counted once
  }
#pragma unroll
  for (int o = 1; o < 64; o <<= 1) blockAcc += __shfl_xor(blockAcc, o);
  if (lane == 0) atomicAdd(&S[Sidx], blockAcc);
}

// K2: bnout (blocks 0..391) + KDE weight per class (blocks 392..398).
__global__ __launch_bounds__(256) void k_final(const float* __restrict__ logits,
                                               const float* __restrict__ S1,
                                               const float* __restrict__ S2,
                                               const float* __restrict__ gamma,
                                               const float* __restrict__ beta,
                                               const float* __restrict__ rs_part,
                                               float* __restrict__ wcl,
                                               float* __restrict__ out) {
  int b = blockIdx.x, t = threadIdx.x;
  if (b < 392) {
    int idx = b * 256 + t;  // 392*256 = 100352 exactly
    int row = idx / 7;
    int c = idx - row * 7;
    float mu = S1[c] * (1.f / 14336.f);
    float var = S2[c] * (1.f / 14336.f) - mu * mu;
    out[idx] = gamma[c] * (logits[idx] - mu) * rsqrtf(var + 1e-5f) + beta[c];
    return;
  }
  int c = b - 392;
  // log_norm = -256*ln(2*pi*0.04) - ln(2048)
  const float LOG_NORM = 345.9110632f;
  float v = 0.f;
  for (int i = t; i < M_CLS; i += 256) {
    int row = c * M_CLS + i;
    float rsum = 0.f;
#pragma unroll
    for (int jj = 0; jj < 32; ++jj) rsum += rs_part[jj * 14336 + row];
    v += 1.f / (logf(rsum) + LOG_NORM);
  }
#pragma unroll
  for (int o = 1; o < 64; o <<= 1) v += __shfl_xor(v, o);
  __shared__ float r[4];
  if ((t & 63) == 0) r[t >> 6] = v;
  __syncthreads();
  if (t == 0) wcl[c] = 1.f / ((r[0] + r[1] + r[2] + r[3]) + 1e-5f);
}

// K3: final affinity loss (tiny).
__global__ void k_aff(const float* __restrict__ S, const float* __restrict__ wcl,
                      float* __restrict__ aff_out) {
  if (threadIdx.x == 0) {
    const float inv_m2 = 1.0f / ((float)M_CLS * (float)M_CLS);
    float aff = 0.f;
#pragma unroll
    for (int i = 0; i < 7; ++i) {
      float Ssrc = S[i];
      float Stgt = (i > 0) ? S[0] : S[1];
      float X    = (i > 0) ? S[6 + i] : S[7];  // cross Sidx 7+p is (p+1,0); X01==X10
      aff -= (Ssrc + Stgt - 2.f * X) * inv_m2 * wcl[i];
    }
    aff_out[0] = aff;
  }
}

extern "C" void kernel_launch(void* const* d_in, const int* in_sizes, int n_in,
                              void* d_out, int out_size, void* d_ws, size_t ws_size,
                              hipStream_t stream) {
  const float* fea   = (const float*)d_in[0];
  const float* W_fc  = (const float*)d_in[1];
  const float* gamma = (const float*)d_in[2];
  const float* beta  = (const float*)d_in[3];
  float* out = (float*)d_out;

  char* ws = (char*)d_ws;
  short* fb = (short*)ws;                        // bf16 fea: 14,680,064 B
  float* fbase   = (float*)(ws + 14680064);
  float* an      = fbase;                        // 14336
  float* logits  = fbase + 14336;                // 100352
  float* zb      = fbase + 114688;               // 64-float zero block
  float* S1      = zb;                           //   [0..6]
  float* S2      = zb + 7;                       //   [7..13]
  float* S       = zb + 16;                      //   [16..28] (13 used)
  float* wcl     = fbase + 114752;               // 7 (pad to 8)
  float* rs_part = fbase + 114760;               // 32*14336 = 458752 (fully written)

  k_prep <<<448,  256, 0, stream>>>(fea, W_fc, fb, an, logits, zb);
  k_gram <<<2544, 256, 0, stream>>>(fb, an, logits, S, rs_part, S1, S2);
  k_final<<<399,  256, 0, stream>>>(logits, S1, S2, gamma, beta, rs_part, wcl, out);
  k_aff  <<<1,    64,  0, stream>>>(S, wcl, out + 100352);
}

// Round 6
// 258.480 us; speedup vs baseline: 1.3531x; 1.0013x over previous
//
#include <hip/hip_runtime.h>

#define B_ROWS 14336
#define D_DIM  512
#define C_CLS  7
#define M_CLS  2048

typedef __attribute__((ext_vector_type(8))) short bf16x8;
typedef __attribute__((ext_vector_type(4))) float f32x4;

typedef const __attribute__((address_space(1))) short gshort_t;
typedef __attribute__((address_space(3))) short lshort_t;

__device__ __forceinline__ void gload16(const short* g, short* l) {
  // async global->LDS DMA, 16B/lane, dest = wave-uniform base + lane*16
  __builtin_amdgcn_global_load_lds((gshort_t*)g, (lshort_t*)l, 16, 0, 0);
}

__device__ __forceinline__ short bf16_rne(float x) {
  unsigned u = __float_as_uint(x);
  u += 0x7fffu + ((u >> 16) & 1u);
  return (short)(u >> 16);
}

// K0: fea->bf16 + row norms + logits + zero small accumulators.
__global__ __launch_bounds__(256) void k_prep(const float* __restrict__ fea,
                                              const float* __restrict__ W,
                                              short* __restrict__ fb,
                                              float* __restrict__ an,
                                              float* __restrict__ logits,
                                              float* __restrict__ zb) {  // 64 floats: S1,S2,S
  int t = threadIdx.x;
  if (blockIdx.x == 0 && t < 64) zb[t] = 0.f;

  int wave = t >> 6, lane = t & 63;
  int gw = blockIdx.x * 4 + wave;
  for (int it = 0; it < 8; ++it) {
    int row = gw + it * 1792;
    const float4* fr4 = (const float4*)(fea + (size_t)row * D_DIM);
    float4 v0 = fr4[lane * 2], v1 = fr4[lane * 2 + 1];
    float s = v0.x * v0.x + v0.y * v0.y + v0.z * v0.z + v0.w * v0.w +
              v1.x * v1.x + v1.y * v1.y + v1.z * v1.z + v1.w * v1.w;
#pragma unroll
    for (int o = 1; o < 64; o <<= 1) s += __shfl_xor(s, o);
    if (lane == 0) an[row] = s;
    int4 pk;
    pk.x = (unsigned short)bf16_rne(v0.x) | ((unsigned)(unsigned short)bf16_rne(v0.y) << 16);
    pk.y = (unsigned short)bf16_rne(v0.z) | ((unsigned)(unsigned short)bf16_rne(v0.w) << 16);
    pk.z = (unsigned short)bf16_rne(v1.x) | ((unsigned)(unsigned short)bf16_rne(v1.y) << 16);
    pk.w = (unsigned short)bf16_rne(v1.z) | ((unsigned)(unsigned short)bf16_rne(v1.w) << 16);
    ((int4*)(fb + (size_t)row * D_DIM))[lane] = pk;
#pragma unroll
    for (int c = 0; c < 7; ++c) {
      const float4* w4 = (const float4*)(W + c * D_DIM);
      float4 w0 = w4[lane * 2], w1 = w4[lane * 2 + 1];
      float p = v0.x * w0.x + v0.y * w0.y + v0.z * w0.z + v0.w * w0.w +
                v1.x * w1.x + v1.y * w1.y + v1.z * w1.z + v1.w * w1.w;
#pragma unroll
      for (int o = 1; o < 64; o <<= 1) p += __shfl_xor(p, o);
      if (lane == 0) logits[row * 7 + c] = p;
    }
  }
}

// K1: fused Gram + exp reductions. 128x128 tile, BK=32, PING-PONG double-buffered
// DMA staging, ONE barrier per kt (prefetch issued post-barrier so the DMA engine
// runs concurrently with compute on the other buffer). XCD-aware grid (r5),
// atomic-free rowsum partials (r5).
__global__ __launch_bounds__(256) void k_gram(const short* __restrict__ fb,
                                              const float* __restrict__ an,
                                              const float* __restrict__ logits,
                                              float* __restrict__ S,
                                              float* __restrict__ rs_part,
                                              float* __restrict__ S1,
                                              float* __restrict__ S2) {
  int unit = blockIdx.x >> 3, xcd = blockIdx.x & 7;
  int t = threadIdx.x, lane = t & 63, wave = t >> 6;

  if (unit >= 311) {  // batch-norm stats partials
    int sidx = (unit - 311) * 8 + xcd;  // 0..55
    int c = sidx >> 3, chunk = sidx & 7;
    int r0 = chunk * 1792;
    float s1 = 0.f, s2 = 0.f;
    for (int j = t; j < 1792; j += 256) {
      float v = logits[(r0 + j) * 7 + c];
      s1 += v;
      s2 += v * v;
    }
#pragma unroll
    for (int o = 1; o < 64; o <<= 1) {
      s1 += __shfl_xor(s1, o);
      s2 += __shfl_xor(s2, o);
    }
    __shared__ float r1_[4], r2_[4];
    if (lane == 0) { r1_[wave] = s1; r2_[wave] = s2; }
    __syncthreads();
    if (t == 0) {
      atomicAdd(&S1[c], r1_[0] + r1_[1] + r1_[2] + r1_[3]);
      atomicAdd(&S2[c], r2_[0] + r2_[1] + r2_[2] + r2_[3]);
    }
    return;
  }

  int c1, c2, TI, TJ, Sidx;
  bool self;
  if (xcd < 7 && unit < 136) {
    int tj = 0, t2 = unit;
    while (t2 > tj) { t2 -= (tj + 1); ++tj; }  // idx = tj*(tj+1)/2 + ti, ti<=tj
    TI = t2; TJ = tj;
    c1 = xcd; c2 = xcd; Sidx = xcd; self = true;
  } else {
    int e = (xcd < 7) ? (xcd * 175 + unit - 136) : (1225 + unit);
    int p = e >> 8;
    int tl = e & 255;
    TJ = tl >> 4; TI = tl & 15;
    c1 = p + 1; c2 = 0; Sidx = 7 + p; self = false;
  }
  bool diag = self && (TI == TJ);
  bool off  = self && (TI < TJ);
  int rowA0 = c1 * M_CLS + TI * 128;
  int rowB0 = c2 * M_CLS + TJ * 128;

  // [buf][tile A/B][128 rows x 32 shorts] = 2 x 8 KB x 2 = 32 KB
  __shared__ short lds[2][2][128 * 32];

  f32x4 acc[4][4];
#pragma unroll
  for (int i = 0; i < 4; ++i)
#pragma unroll
    for (int j = 0; j < 4; ++j)
      acc[i][j] = (f32x4){0.f, 0.f, 0.f, 0.f};

  int wr = wave >> 1, wc = wave & 1;  // 2x2 waves of 64x64
  int q = lane >> 4, s = lane & 15;

  // --- staging geometry (per DMA instr: 16 rows x 64 B = 1 KB) ---
  // dest lane -> (row j = lane>>2, phys seg p = lane&3); source logical seg
  // l = p ^ a'(j) with a'(r) = (r ^ (r>>2)) & 3 (bijective row swizzle).
  int j_ = lane >> 2;
  int lseg = (lane & 3) ^ ((j_ ^ (j_ >> 2)) & 3);
  size_t srcA = (size_t)(rowA0 + j_) * D_DIM + lseg * 8;  // + wrow*512 + kt*32
  size_t srcB = (size_t)(rowB0 + j_) * D_DIM + lseg * 8;
  // fragment-read phys seg: q ^ a'(s)
  int psF = ((q ^ (s ^ (s >> 2))) & 3) * 8;

  int r0a = wave * 32, r0b = wave * 32 + 16;  // two 16-row chunks per wave

#define STAGE(kt_, b_)                                                        \
  do {                                                                        \
    int k0_ = (kt_) * 32;                                                     \
    gload16(fb + srcA + (size_t)r0a * D_DIM + k0_, &lds[b_][0][r0a * 32]);    \
    gload16(fb + srcA + (size_t)r0b * D_DIM + k0_, &lds[b_][0][r0b * 32]);    \
    if (!diag) {                                                              \
      gload16(fb + srcB + (size_t)r0a * D_DIM + k0_, &lds[b_][1][r0a * 32]);  \
      gload16(fb + srcB + (size_t)r0b * D_DIM + k0_, &lds[b_][1][r0b * 32]);  \
    }                                                                         \
  } while (0)

  STAGE(0, 0);  // prime
  for (int kt = 0; kt < 16; ++kt) {
    int b = kt & 1;
    __syncthreads();            // drains buf b's DMA (in flight one compute phase)
    if (kt < 15) STAGE(kt + 1, b ^ 1);
    const short* A  = lds[b][0];
    const short* Bp = diag ? lds[b][0] : lds[b][1];
    bf16x8 af[4], bfv[4];
#pragma unroll
    for (int mi = 0; mi < 4; ++mi)
      af[mi] = *(const bf16x8*)&A[(wr * 64 + mi * 16 + s) * 32 + psF];
#pragma unroll
    for (int mj = 0; mj < 4; ++mj)
      bfv[mj] = *(const bf16x8*)&Bp[(wc * 64 + mj * 16 + s) * 32 + psF];
#pragma unroll
    for (int mi = 0; mi < 4; ++mi)
#pragma unroll
      for (int mj = 0; mj < 4; ++mj)
        acc[mi][mj] = __builtin_amdgcn_mfma_f32_16x16x32_bf16(
            af[mi], bfv[mj], acc[mi][mj], 0, 0, 0);
  }
#undef STAGE

  // row norms into registers (L2-hot)
  float anA[4][4], anB[4];
#pragma unroll
  for (int mi = 0; mi < 4; ++mi)
#pragma unroll
    for (int rg = 0; rg < 4; ++rg)
      anA[mi][rg] = an[rowA0 + wr * 64 + mi * 16 + q * 4 + rg];
#pragma unroll
  for (int mj = 0; mj < 4; ++mj)
    anB[mj] = an[rowB0 + wc * 64 + mj * 16 + s];

  // Epilogue. C/D layout (16x16x32): col = lane&15, row = (lane>>4)*4 + reg.
  // 5-kernel sum via exp-squaring from e1 = exp(-0.05*d2).
  float blockAcc = 0.f;
  float colAcc[4] = {0.f, 0.f, 0.f, 0.f};
  float* dirP = rs_part + (size_t)(TJ * 2 + wc) * 14336 + rowA0;
#pragma unroll
  for (int mi = 0; mi < 4; ++mi) {
#pragma unroll
    for (int rg = 0; rg < 4; ++rg) {
      int rl = wr * 64 + mi * 16 + q * 4 + rg;
      float aA = anA[mi][rg];
      float rowAcc = 0.f;
#pragma unroll
      for (int mj = 0; mj < 4; ++mj) {
        int cl = wc * 64 + mj * 16 + s;
        float g = acc[mi][mj][rg];
        float d2 = fmaxf(aA + anB[mj] - 2.f * g, 0.f);
        if (diag && rl == cl) d2 = 0.f;  // exact diagonal
        float e1 = __expf(-0.05f * d2);
        float e2 = e1 * e1, e4 = e2 * e2, e8 = e4 * e4, e16 = e8 * e8;
        blockAcc += e1 + e2 + e4 + e8 + e16;
        if (self) {
          float ek = __expf(-12.5f * d2);  // KDE: 1/(2*0.2^2)
          rowAcc += ek;
          if (off) colAcc[mj] += ek;
        }
      }
      if (self) {
        rowAcc += __shfl_xor(rowAcc, 1);
        rowAcc += __shfl_xor(rowAcc, 2);
        rowAcc += __shfl_xor(rowAcc, 4);
        rowAcc += __shfl_xor(rowAcc, 8);
        if (s == 0) dirP[rl] = rowAcc;
      }
    }
  }
  if (off) {
    float* mirP = rs_part + (size_t)(TI * 2 + wr) * 14336 + rowB0;
#pragma unroll
    for (int mj = 0; mj < 4; ++mj) {
      float v = colAcc[mj];
      v += __shfl_xor(v, 16);
      v += __shfl_xor(v, 32);
      if (q == 0) mirP[wc * 64 + mj * 16 + s] = v;
    }
    blockAcc *= 2.f;  // mirror tile counted once
  }
#pragma unroll
  for (int o = 1; o < 64; o <<= 1) blockAcc += __shfl_xor(blockAcc, o);
  if (lane == 0) atomicAdd(&S[Sidx], blockAcc);
}

// K2: bnout (blocks 0..391) + KDE weight per class (blocks 392..398).
__global__ __launch_bounds__(256) void k_final(const float* __restrict__ logits,
                                               const float* __restrict__ S1,
                                               const float* __restrict__ S2,
                                               const float* __restrict__ gamma,
                                               const float* __restrict__ beta,
                                               const float* __restrict__ rs_part,
                                               float* __restrict__ wcl,
                                               float* __restrict__ out) {
  int b = blockIdx.x, t = threadIdx.x;
  if (b < 392) {
    int idx = b * 256 + t;  // 392*256 = 100352 exactly
    int row = idx / 7;
    int c = idx - row * 7;
    float mu = S1[c] * (1.f / 14336.f);
    float var = S2[c] * (1.f / 14336.f) - mu * mu;
    out[idx] = gamma[c] * (logits[idx] - mu) * rsqrtf(var + 1e-5f) + beta[c];
    return;
  }
  int c = b - 392;
  // log_norm = -256*ln(2*pi*0.04) - ln(2048)
  const float LOG_NORM = 345.9110632f;
  float v = 0.f;
  for (int i = t; i < M_CLS; i += 256) {
    int row = c * M_CLS + i;
    float rsum = 0.f;
#pragma unroll
    for (int jj = 0; jj < 32; ++jj) rsum += rs_part[jj * 14336 + row];
    v += 1.f / (logf(rsum) + LOG_NORM);
  }
#pragma unroll
  for (int o = 1; o < 64; o <<= 1) v += __shfl_xor(v, o);
  __shared__ float r[4];
  if ((t & 63) == 0) r[t >> 6] = v;
  __syncthreads();
  if (t == 0) wcl[c] = 1.f / ((r[0] + r[1] + r[2] + r[3]) + 1e-5f);
}

// K3: final affinity loss (tiny).
__global__ void k_aff(const float* __restrict__ S, const float* __restrict__ wcl,
                      float* __restrict__ aff_out) {
  if (threadIdx.x == 0) {
    const float inv_m2 = 1.0f / ((float)M_CLS * (float)M_CLS);
    float aff = 0.f;
#pragma unroll
    for (int i = 0; i < 7; ++i) {
      float Ssrc = S[i];
      float Stgt = (i > 0) ? S[0] : S[1];
      float X    = (i > 0) ? S[6 + i] : S[7];  // cross Sidx 7+p is (p+1,0); X01==X10
      aff -= (Ssrc + Stgt - 2.f * X) * inv_m2 * wcl[i];
    }
    aff_out[0] = aff;
  }
}

extern "C" void kernel_launch(void* const* d_in, const int* in_sizes, int n_in,
                              void* d_out, int out_size, void* d_ws, size_t ws_size,
                              hipStream_t stream) {
  const float* fea   = (const float*)d_in[0];
  const float* W_fc  = (const float*)d_in[1];
  const float* gamma = (const float*)d_in[2];
  const float* beta  = (const float*)d_in[3];
  float* out = (float*)d_out;

  char* ws = (char*)d_ws;
  short* fb = (short*)ws;                        // bf16 fea: 14,680,064 B
  float* fbase   = (float*)(ws + 14680064);
  float* an      = fbase;                        // 14336
  float* logits  = fbase + 14336;                // 100352
  float* zb      = fbase + 114688;               // 64-float zero block
  float* S1      = zb;                           //   [0..6]
  float* S2      = zb + 7;                       //   [7..13]
  float* S       = zb + 16;                      //   [16..28] (13 used)
  float* wcl     = fbase + 114752;               // 7 (pad to 8)
  float* rs_part = fbase + 114760;               // 32*14336 = 458752 (fully written)

  k_prep <<<448,  256, 0, stream>>>(fea, W_fc, fb, an, logits, zb);
  k_gram <<<2544, 256, 0, stream>>>(fb, an, logits, S, rs_part, S1, S2);
  k_final<<<399,  256, 0, stream>>>(logits, S1, S2, gamma, beta, rs_part, wcl, out);
  k_aff  <<<1,    64,  0, stream>>>(S, wcl, out + 100352);
}